// Round 10
// baseline (136.788 us; speedup 1.0000x reference)
//
#include <hip/hip_runtime.h>
#include <hip/hip_bf16.h>
#include <stdint.h>

// GPT2Attention: S=2048 E=1024 H=16 d=64 T=4096 past=2048, f32 in/out.
// Round 10: attn moved to 32x32x16 MFMA with fully in-register P relayout
// (swapped QK -> P lane-local; pack + 2 shfl_xor(32) per k-slice replaces the
// P LDS round-trip). 16 b128 frag reads/tile (was 20 + 8 writes). LDS 32KB ->
// 4 blocks/CU. Grid/chunking/head-affinity/merge unchanged from round 9.

#define S_LEN 2048
#define E_DIM 1024
#define NHEAD 16
#define HDIM  64
#define T_LEN 4096
#define PASTL 2048

typedef __bf16 bf16x8 __attribute__((ext_vector_type(8)));
typedef float  f32x4  __attribute__((ext_vector_type(4)));
typedef float  f32x16 __attribute__((ext_vector_type(16)));

static __device__ __forceinline__ f32x4 mfma_bf16(bf16x8 a, bf16x8 b, f32x4 c) {
  return __builtin_amdgcn_mfma_f32_16x16x32_bf16(a, b, c, 0, 0, 0);
}
static __device__ __forceinline__ f32x16 mfma32(bf16x8 a, bf16x8 b, f32x16 c) {
  return __builtin_amdgcn_mfma_f32_32x32x16_bf16(a, b, c, 0, 0, 0);
}

// RNE float -> bf16 bits (values are finite; no NaN path needed)
static __device__ __forceinline__ unsigned int f2bf(float f) {
  union { float f; unsigned int u; } v; v.f = f;
  unsigned int u = v.u;
  return (u + 0x7fffu + ((u >> 16) & 1u)) >> 16;
}

static __device__ __forceinline__ float bf2f(unsigned short u) {
  union { unsigned int u; float f; } v; v.u = (unsigned int)u << 16;
  return v.f;
}

#define GLOBAL_LOAD_LDS16(gptr, lptr)                                              \
  __builtin_amdgcn_global_load_lds(                                                \
      (const __attribute__((address_space(1))) unsigned int*)(gptr),               \
      (__attribute__((address_space(3))) unsigned int*)(lptr), 16, 0, 0)

// ---------------------------------------------------------------- aux kernels

__global__ void copy_past_kernel(const float* __restrict__ past,
                                 float* __restrict__ cache,
                                 unsigned short* __restrict__ kb) {
  const int n4 = (2 * NHEAD * PASTL * HDIM) / 4;
  for (int i = blockIdx.x * blockDim.x + threadIdx.x; i < n4;
       i += gridDim.x * blockDim.x) {
    int e = i * 4;
    int d = e & 63;
    int t = (e >> 6) & (PASTL - 1);
    int hh = (e >> 17) & (NHEAD - 1);
    int kv = e >> 21;
    size_t full = (((size_t)kv * NHEAD + hh) * T_LEN + t) * HDIM + d;
    float4 v = *(const float4*)(past + full);
    *(float4*)(cache + full) = v;
    if (kv == 0) {
      ushort4 u;
      u.x = f2bf(v.x); u.y = f2bf(v.y); u.z = f2bf(v.z); u.w = f2bf(v.w);
      *(ushort4*)(kb + full) = u;
    }
  }
}

__global__ void convert_kernel(const float* __restrict__ in,
                               unsigned short* __restrict__ out, int n4) {
  for (int i = blockIdx.x * blockDim.x + threadIdx.x; i < n4;
       i += gridDim.x * blockDim.x) {
    float4 v = ((const float4*)in)[i];
    ushort4 u;
    u.x = f2bf(v.x); u.y = f2bf(v.y); u.z = f2bf(v.z); u.w = f2bf(v.w);
    ((ushort4*)out)[i] = u;
  }
}

// in [rows][cols] f32 -> out [cols][rows] bf16
__global__ void transpose_convert_kernel(const float* __restrict__ in,
                                         unsigned short* __restrict__ out,
                                         int rows, int cols) {
  __shared__ float tile[64][65];
  const int c0 = blockIdx.x * 64, r0 = blockIdx.y * 64;
  const int tx = threadIdx.x & 63, ty = threadIdx.x >> 6;
#pragma unroll
  for (int r = 0; r < 64; r += 4)
    tile[r + ty][tx] = in[(size_t)(r0 + r + ty) * cols + c0 + tx];
  __syncthreads();
#pragma unroll
  for (int r = 0; r < 64; r += 4)
    out[(size_t)(c0 + r + ty) * rows + r0 + tx] = f2bf(tile[tx][r + ty]);
}

// cache_v f32 [H][T][64] -> vt bf16 [H][64][T]
__global__ void vtrans_kernel(const float* __restrict__ vin,
                              unsigned short* __restrict__ vt) {
  __shared__ float tile[64][65];
  const int h = blockIdx.y;
  const int t0 = blockIdx.x * 64;
  const float* in = vin + (size_t)h * T_LEN * HDIM;
  unsigned short* out = vt + (size_t)h * HDIM * T_LEN;
  const int tx = threadIdx.x & 63, ty = threadIdx.x >> 6;
#pragma unroll
  for (int r = 0; r < 64; r += 4)
    tile[r + ty][tx] = in[(size_t)(t0 + r + ty) * HDIM + tx];
  __syncthreads();
#pragma unroll
  for (int r = 0; r < 64; r += 4)
    out[(size_t)(r + ty) * T_LEN + t0 + tx] = f2bf(tile[tx][r + ty]);
}

// ---------------------------------------------------------------- GEMM (B^T)
// MODE 0: c_attn epilogue (q*0.125*log2e->bf16, k->cache+bf16, v->cache).
// MODE 1: f32 out.
template <int MODE>
__global__ __launch_bounds__(256) void gemm_bt_kernel(
    const unsigned short* __restrict__ A, const unsigned short* __restrict__ Bt,
    const float* __restrict__ bias, int K,
    float* __restrict__ out_f32, unsigned short* __restrict__ qb,
    float* __restrict__ cache_k, float* __restrict__ cache_v,
    unsigned short* __restrict__ kb) {
  __shared__ alignas(16) unsigned short As[128 * 64];
  __shared__ alignas(16) unsigned short Bs[128 * 64];
  const int tid = threadIdx.x;
  const int lane = tid & 63;
  const int w = tid >> 6;
  const int wm = w >> 1, wn = w & 1;
  const int m0 = blockIdx.y * 128, n0 = blockIdx.x * 128;

  f32x4 acc[4][4];
#pragma unroll
  for (int i = 0; i < 4; ++i)
#pragma unroll
    for (int j = 0; j < 4; ++j) acc[i][j] = f32x4{0.f, 0.f, 0.f, 0.f};

  const int rbase = w * 8 + (lane >> 3);
  const int sbase = lane & 7;

  for (int k0 = 0; k0 < K; k0 += 64) {
#pragma unroll
    for (int q = 0; q < 4; ++q) {
      int row_l = q * 32 + rbase;
      int slot = sbase ^ (row_l & 7);
      const unsigned short* ga = A + (size_t)(m0 + row_l) * K + k0 + slot * 8;
      const unsigned short* gb = Bt + (size_t)(n0 + row_l) * K + k0 + slot * 8;
      unsigned int ldsOff = (unsigned int)(q * 4096 + w * 1024);
      GLOBAL_LOAD_LDS16(ga, (char*)As + ldsOff);
      GLOBAL_LOAD_LDS16(gb, (char*)Bs + ldsOff);
    }
    __syncthreads();
#pragma unroll
    for (int kk = 0; kk < 2; ++kk) {
      bf16x8 af[4], bfr[4];
#pragma unroll
      for (int mi = 0; mi < 4; ++mi) {
        int row = wm * 64 + mi * 16 + (lane & 15);
        int slot = (kk * 4 + (lane >> 4)) ^ (row & 7);
        af[mi] = *reinterpret_cast<const bf16x8*>((const char*)As + row * 128 + slot * 16);
      }
#pragma unroll
      for (int ni = 0; ni < 4; ++ni) {
        int row = wn * 64 + ni * 16 + (lane & 15);
        int slot = (kk * 4 + (lane >> 4)) ^ (row & 7);
        bfr[ni] = *reinterpret_cast<const bf16x8*>((const char*)Bs + row * 128 + slot * 16);
      }
#pragma unroll
      for (int mi = 0; mi < 4; ++mi)
#pragma unroll
        for (int ni = 0; ni < 4; ++ni)
          acc[mi][ni] = mfma_bf16(af[mi], bfr[ni], acc[mi][ni]);
    }
    __syncthreads();
  }

#pragma unroll
  for (int ni = 0; ni < 4; ++ni) {
    int n = n0 + wn * 64 + ni * 16 + (lane & 15);
    float bv = bias[n];
#pragma unroll
    for (int mi = 0; mi < 4; ++mi) {
#pragma unroll
      for (int r = 0; r < 4; ++r) {
        int m = m0 + wm * 64 + mi * 16 + (lane >> 4) * 4 + r;
        float val = acc[mi][ni][r] + bv;
        if (MODE == 0) {
          if (n < E_DIM) {
            // fold 1/sqrt(d) * log2(e) for exp2-softmax
            qb[(size_t)m * E_DIM + n] = f2bf(val * 0.18033688f);
          } else if (n < 2 * E_DIM) {
            int e = n - E_DIM;
            size_t idx = ((size_t)(e >> 6) * T_LEN + (PASTL + m)) * HDIM + (e & 63);
            cache_k[idx] = val;
            kb[idx] = f2bf(val);
          } else {
            int e = n - 2 * E_DIM;
            size_t idx = ((size_t)(e >> 6) * T_LEN + (PASTL + m)) * HDIM + (e & 63);
            cache_v[idx] = val;
          }
        } else {
          out_f32[(size_t)m * E_DIM + n] = val;
        }
      }
    }
  }
}

// ---------------------------------------------------------------- attention
// 4 waves (256 thr)/block, 32 q-rows/wave, KVBLK=64, 32x32x16 MFMA.
// Swapped QK (A=K,B=Q): D col=lane&31=q, row key=(r&3)+8(r>>2)+4hi (m74/m101).
// P stays in registers: pack pairs -> dwords, 2 shfl_xor(32) per k-slice builds
// the PV A-frag (lane q-local). V-frags read before softmax (independent).
// Grid: 896 blocks, r9 chunk decomposition + XCD head-affinity. No p_lds.
__global__ __launch_bounds__(256, 4) void attn_kernel(
    const unsigned short* __restrict__ qb, const unsigned short* __restrict__ kb,
    const unsigned short* __restrict__ vt,
    unsigned short* __restrict__ o_part, float* __restrict__ l_part) {
  __shared__ alignas(16) unsigned short Ks[2][64 * 64];
  __shared__ alignas(16) unsigned short Vs[2][64 * 64];
  const int fid = blockIdx.x;  // 0..895
  const int h = (fid & 7) + ((fid >= 448) ? 8 : 0);
  const int g = (fid >> 3) - ((fid >= 448) ? 56 : 0);  // 0..55
  int x, c;
  if (g < 24) { x = g / 3; c = g - 3 * x; }
  else { int g2 = g - 24; x = 8 + (g2 >> 2); c = g2 & 3; }

  const int tid = threadIdx.x;
  const int w = tid >> 6;
  const int lane = tid & 63;
  const int l31 = lane & 31;
  const int hi = lane >> 5;
  const int hi4 = hi * 4;
  const int q0 = x * 128 + w * 32;

  // Q B-frags: lane (col=q=l31, hi) holds d = kk*16 + hi*8 + 0..7
  const unsigned short* qrow = qb + (size_t)(q0 + l31) * E_DIM + h * HDIM + hi * 8;
  bf16x8 qf[4];
#pragma unroll
  for (int kk = 0; kk < 4; ++kk)
    qf[kk] = *reinterpret_cast<const bf16x8*>(qrow + kk * 16);

  const unsigned short* kh = kb + (size_t)h * T_LEN * HDIM;
  const unsigned short* vh = vt + (size_t)h * HDIM * T_LEN;

  // staging: thread (srow=tid>>3 in 0..31, seg=tid&7); linear LDS dest,
  // source seg pre-swizzled with f(row)=row&7 (invariant under +32).
  const int srow = tid >> 3;
  const int sseg = (tid & 7) ^ (srow & 7);
  const unsigned short* ksrc = kh + (size_t)srow * HDIM + sseg * 8;
  const unsigned short* vsrc = vh + (size_t)srow * T_LEN + sseg * 8;

  f32x16 o0, o1;
#pragma unroll
  for (int i = 0; i < 16; ++i) { o0[i] = 0.f; o1[i] = 0.f; }
  float lsum = 0.f;

  const int NTfull = 34 + 2 * x;
  const int tb = c * 16;
  const int te = (tb + 16 < NTfull) ? tb + 16 : NTfull;
  const int tbeg = tb * 64, tend = te * 64;
  const int qpp = q0 + l31 + PASTL;  // key > qpp => masked

  auto stage = [&](int b, int t0) {
    GLOBAL_LOAD_LDS16(ksrc + (size_t)t0 * HDIM, (char*)Ks[b] + tid * 16);
    GLOBAL_LOAD_LDS16(ksrc + (size_t)(t0 + 32) * HDIM, (char*)Ks[b] + 4096 + tid * 16);
    GLOBAL_LOAD_LDS16(vsrc + t0, (char*)Vs[b] + tid * 16);
    GLOBAL_LOAD_LDS16(vsrc + t0 + (size_t)32 * T_LEN, (char*)Vs[b] + 4096 + tid * 16);
  };

  stage(0, tbeg);
  int cur = 0;
  for (int t0 = tbeg; t0 < tend; t0 += 64) {
    asm volatile("s_waitcnt vmcnt(0)" ::: "memory");
    __syncthreads();
    if (t0 + 64 < tend) stage(cur ^ 1, t0 + 64);

    // ---- QK^T (swapped): A=K frags from LDS, B=Q regs ----
    f32x16 s0, s1;
#pragma unroll
    for (int i = 0; i < 16; ++i) { s0[i] = 0.f; s1[i] = 0.f; }
    __builtin_amdgcn_s_setprio(1);
#pragma unroll
    for (int kk = 0; kk < 4; ++kk) {
      int row0 = l31, row1 = 32 + l31;
      int sl0 = (kk * 2 + hi) ^ (row0 & 7);
      int sl1 = (kk * 2 + hi) ^ (row1 & 7);
      bf16x8 kf0 = *reinterpret_cast<const bf16x8*>((const char*)Ks[cur] + row0 * 128 + sl0 * 16);
      bf16x8 kf1 = *reinterpret_cast<const bf16x8*>((const char*)Ks[cur] + row1 * 128 + sl1 * 16);
      s0 = mfma32(kf0, qf[kk], s0);
      s1 = mfma32(kf1, qf[kk], s1);
    }
    __builtin_amdgcn_s_setprio(0);

    // ---- V B-frags (independent of P; issue before softmax) ----
    bf16x8 vf0[4], vf1[4];
#pragma unroll
    for (int ks = 0; ks < 4; ++ks) {
      int row0 = l31, row1 = 32 + l31;
      int sl0 = (ks * 2 + hi) ^ (row0 & 7);
      int sl1 = (ks * 2 + hi) ^ (row1 & 7);
      vf0[ks] = *reinterpret_cast<const bf16x8*>((const char*)Vs[cur] + row0 * 128 + sl0 * 16);
      vf1[ks] = *reinterpret_cast<const bf16x8*>((const char*)Vs[cur] + row1 * 128 + sl1 * 16);
    }

    // ---- softmax (no-max, exp2) + pack to dwords, fully in-register ----
    const bool partial = (t0 + 63 > q0 + PASTL);
    const int thr = qpp - t0;
    unsigned int dw0[8], dw1[8];
#pragma unroll
    for (int i = 0; i < 8; ++i) {
      int r0 = 2 * i;
      int ko = (r0 & 3) + 8 * (r0 >> 2) + hi4;  // key offset within 32-block
      float p0 = __builtin_amdgcn_exp2f(s0[r0]);
      float p1 = __builtin_amdgcn_exp2f(s0[r0 + 1]);
      float p2 = __builtin_amdgcn_exp2f(s1[r0]);
      float p3 = __builtin_amdgcn_exp2f(s1[r0 + 1]);
      if (partial) {
        if (ko > thr) p0 = 0.f;
        if (ko + 1 > thr) p1 = 0.f;
        if (ko + 32 > thr) p2 = 0.f;
        if (ko + 33 > thr) p3 = 0.f;
      }
      lsum += (p0 + p1) + (p2 + p3);
      dw0[i] = (f2bf(p1) << 16) | f2bf(p0);
      dw1[i] = (f2bf(p3) << 16) | f2bf(p2);
    }

    // ---- build PV A-frags: pa[ks] via 2 shfl_xor(32) each ----
    bf16x8 pa[4];
#pragma unroll
    for (int ks = 0; ks < 4; ++ks) {
      const unsigned int* dwp = (ks < 2) ? dw0 : dw1;
      int base = 4 * (ks & 1);
      unsigned int lo0 = dwp[base + 0], lo1 = dwp[base + 1];
      unsigned int hi0 = dwp[base + 2], hi1 = dwp[base + 3];
      unsigned int s_0 = hi ? lo0 : hi0;
      unsigned int s_1 = hi ? lo1 : hi1;
      unsigned int r_0 = __shfl_xor((int)s_0, 32);
      unsigned int r_1 = __shfl_xor((int)s_1, 32);
      union { unsigned int u[4]; bf16x8 v; } pu;
      pu.u[0] = hi ? r_0 : lo0;
      pu.u[1] = hi ? r_1 : lo1;
      pu.u[2] = hi ? hi0 : r_0;
      pu.u[3] = hi ? hi1 : r_1;
      pa[ks] = pu.v;
    }

    // ---- PV: o[db] += P * V ----
    __builtin_amdgcn_s_setprio(1);
#pragma unroll
    for (int ks = 0; ks < 4; ++ks) {
      o0 = mfma32(pa[ks], vf0[ks], o0);
      o1 = mfma32(pa[ks], vf1[ks], o1);
    }
    __builtin_amdgcn_s_setprio(0);
    cur ^= 1;
  }

  lsum += __shfl_xor(lsum, 32);

  // partials: o_part[c][h][row][d] bf16, l_part[c][h][row] f32
  unsigned short* op = o_part + ((size_t)(c * NHEAD + h) * S_LEN) * HDIM;
  float* lp = l_part + (size_t)(c * NHEAD + h) * S_LEN;
  if (hi == 0) lp[q0 + l31] = lsum;
#pragma unroll
  for (int r = 0; r < 16; ++r) {
    int qr = (r & 3) + 8 * (r >> 2) + hi4;
    op[(size_t)(q0 + qr) * HDIM + l31] = f2bf(o0[r]);
    op[(size_t)(q0 + qr) * HDIM + 32 + l31] = f2bf(o1[r]);
  }
}

// Merge chunk partials (3 for rows<1024, 4 otherwise) and normalize -> ab bf16.
__global__ __launch_bounds__(256) void attn_merge_kernel(
    const unsigned short* __restrict__ o_part, const float* __restrict__ l_part,
    unsigned short* __restrict__ ab) {
  const int flat = blockIdx.x * 256 + threadIdx.x;
  const int d4 = flat & 15;
  const int row = (flat >> 4) & (S_LEN - 1);
  const int h = flat >> 15;
  const int nc = (row < 1024) ? 3 : 4;
  const size_t cstride_o = (size_t)NHEAD * S_LEN * HDIM;
  const size_t base_o = (((size_t)h * S_LEN) + row) * HDIM + d4 * 4;
  float acc[4] = {0.f, 0.f, 0.f, 0.f};
  float l = 0.f;
  for (int cc = 0; cc < nc; ++cc) {
    ushort4 u = *(const ushort4*)(o_part + cc * cstride_o + base_o);
    acc[0] += bf2f(u.x); acc[1] += bf2f(u.y);
    acc[2] += bf2f(u.z); acc[3] += bf2f(u.w);
    l += l_part[(size_t)cc * NHEAD * S_LEN + (size_t)h * S_LEN + row];
  }
  float inv = 1.f / l;
  ushort4 u;
  u.x = f2bf(acc[0] * inv);
  u.y = f2bf(acc[1] * inv);
  u.z = f2bf(acc[2] * inv);
  u.w = f2bf(acc[3] * inv);
  *(ushort4*)(ab + (size_t)row * E_DIM + h * HDIM + d4 * 4) = u;
}

// ---------------------------------------------------------------- launch

extern "C" void kernel_launch(void* const* d_in, const int* in_sizes, int n_in,
                              void* d_out, int out_size, void* d_ws, size_t ws_size,
                              hipStream_t stream) {
  (void)in_sizes; (void)n_in; (void)out_size; (void)ws_size;
  const float* x    = (const float*)d_in[0];
  const float* past = (const float*)d_in[1];
  const float* W1   = (const float*)d_in[2];
  const float* b1   = (const float*)d_in[3];
  const float* W2   = (const float*)d_in[4];
  const float* b2   = (const float*)d_in[5];

  float* out = (float*)d_out;
  float* cache_k = out + (size_t)S_LEN * E_DIM;
  float* cache_v = cache_k + (size_t)NHEAD * T_LEN * HDIM;

  // Workspace (~42.5 MB), lifetime-disjoint overlaps:
  //   [0,4)   xb -> ab ; [4,12) w1t -> vt ; [12,14) w2t
  //   [14,18) qb ; [18,26) kb ; [26,42) o_part bf16 [4][16][2048][64]
  //   [42,42.5) l_part f32 [4][16][2048]
  char* ws = (char*)d_ws;
  unsigned short* xb  = (unsigned short*)(ws);
  unsigned short* ab  = (unsigned short*)(ws);
  unsigned short* w1t = (unsigned short*)(ws + (size_t)(4u  << 20));
  unsigned short* vt  = (unsigned short*)(ws + (size_t)(4u  << 20));
  unsigned short* w2t = (unsigned short*)(ws + (size_t)(12u << 20));
  unsigned short* qb  = (unsigned short*)(ws + (size_t)(14u << 20));
  unsigned short* kb  = (unsigned short*)(ws + (size_t)(18u << 20));
  unsigned short* o_part = (unsigned short*)(ws + (size_t)(26u << 20));
  float* l_part = (float*)(ws + (size_t)(42u << 20));

  copy_past_kernel<<<2048, 256, 0, stream>>>(past, cache_k, kb);
  convert_kernel<<<1024, 256, 0, stream>>>(x, xb, (S_LEN * E_DIM) / 4);
  transpose_convert_kernel<<<dim3(3072 / 64, 1024 / 64), 256, 0, stream>>>(W1, w1t, 1024, 3072);
  transpose_convert_kernel<<<dim3(1024 / 64, 1024 / 64), 256, 0, stream>>>(W2, w2t, 1024, 1024);
  gemm_bt_kernel<0><<<dim3(3072 / 128, 2048 / 128), 256, 0, stream>>>(
      xb, w1t, b1, 1024, nullptr, qb, cache_k, cache_v, kb);
  vtrans_kernel<<<dim3(T_LEN / 64, NHEAD), 256, 0, stream>>>(cache_v, vt);
  attn_kernel<<<dim3(896), 256, 0, stream>>>(qb, kb, vt, o_part, l_part);
  attn_merge_kernel<<<(NHEAD * S_LEN * 16) / 256, 256, 0, stream>>>(o_part, l_part, ab);
  gemm_bt_kernel<1><<<dim3(1024 / 128, 2048 / 128), 256, 0, stream>>>(
      ab, w2t, b2, 1024, out, nullptr, nullptr, nullptr, nullptr);
}